// Round 5
// baseline (10080.685 us; speedup 1.0000x reference)
//
#include <hip/hip_runtime.h>
#include <stdint.h>

// Problem constants
#define BB   64
#define TT   250
#define INN  1024
#define HIDD 2048
#define OUTT 256

#define DECAYF 0.951229424500714f   // exp(-1/20)
#define ALPHAF 0.951229424500714f
#define LRF    1e-4f
#define WDF    0.01f
#define SCLF   0.2f

// block roles
#define N_L1   128               // w_in tiles [16h x 1024] bf16, LDS-resident
#define N_L2   16                // w_hid rows [16o x 2048] f32, global block-private
#define N_HELP 8                 // in_tr state in LDS; publishes in_tr^T
#define NBLK   152u

// d_out offsets (float elements), return order:
// l1_seq [64,250,2048], l2_seq [64,250,256], v1, v2, l1_tr, l2_tr
#define O_L1SEQ 0
#define O_L2SEQ 32768000
#define O_V1    36864000
#define O_V2    36995072
#define O_L1TR  37011456
#define O_L2TR  37142528

// workspace (byte offsets): ONLY cross-block data (accessed via agent-coherent ops)
#define WS_INTRT 0u        // bf16 [2][1024][64]  in_tr^T  (outer1 B)
#define WS_L1B   262144u   // bf16 [2][64][2048]  l1 spikes (gemm2 A)
#define WS_L1TRT 786432u   // bf16 [2][2048][64]  l1_tr^T  (outer2 B)
#define WS_BAR   1310720u  // u32 monotonic barrier counter

typedef __attribute__((ext_vector_type(8))) short short8v;
typedef __attribute__((ext_vector_type(4))) float float4v;
typedef unsigned long long u64;

__device__ inline short f2bf(float f) {
  union { float f; uint32_t u; } c; c.f = f;
  uint32_t u = c.u + 0x7fffu + ((c.u >> 16) & 1u);  // RNE
  return (short)(u >> 16);
}
__device__ inline float bf2f(short s) {
  union { uint32_t u; float f; } c; c.u = ((uint32_t)(uint16_t)s) << 16;
  return c.f;
}

// ---- agent-coherent (LLC-point) accessors for cross-block buffers ----
__device__ inline u64 cld(const short* p) {
  return __hip_atomic_load((const u64*)p, __ATOMIC_RELAXED, __HIP_MEMORY_SCOPE_AGENT);
}
__device__ inline void cst(short* p, u64 v) {
  __hip_atomic_store((u64*)p, v, __ATOMIC_RELAXED, __HIP_MEMORY_SCOPE_AGENT);
}
__device__ inline void cst16(short* p, short v) {
  __hip_atomic_store((unsigned short*)p, (unsigned short)v,
                     __ATOMIC_RELAXED, __HIP_MEMORY_SCOPE_AGENT);
}

// ---- grid barrier: monotonic counter, NO cache flush.
// Visibility: cross-block data goes through agent-coherent ops (LLC);
// __syncthreads drains each thread's vmem (compiler emits vmcnt(0) before
// s_barrier), so by the time tid0 adds, all this block's coherent stores
// are at the LLC.
__device__ inline void gbar(unsigned* cnt, unsigned target, int tid) {
  asm volatile("s_waitcnt vmcnt(0)" ::: "memory");
  __syncthreads();
  if (tid == 0) {
    __hip_atomic_fetch_add(cnt, 1u, __ATOMIC_RELAXED, __HIP_MEMORY_SCOPE_AGENT);
    while (__hip_atomic_load(cnt, __ATOMIC_RELAXED, __HIP_MEMORY_SCOPE_AGENT) < target)
      __builtin_amdgcn_s_sleep(2);
  }
  __syncthreads();
}

// MFMA 16x16x32 bf16 layout (verified): A/B frag: lane holds row lane&15, 8
// contiguous k at k0=(lane>>4)*8; C/D: col=lane&15, row=(lane>>4)*4+reg.

// ================= layer-1 block: bid in [0,128), h-tile = bid*16 =================
// LDS: w bf16 [16][1032] @0; stg0 @33024; stg1 @51456 (each 18432); scr f32 [16][68] @69888
__device__ void l1_work(int t, int bid, int tid, const float* __restrict__ x,
                        float* __restrict__ out, char* __restrict__ ws,
                        short* w, short* stg0, short* stg1, float* scr,
                        float4v& v1, float4v& tr1) {
  const int h0 = bid * 16, wv = tid >> 6, lane = tid & 63;
  const int col = lane & 15, q = lane >> 4;

  // ---- gemm1: cur1[64b x 16h], A = x_t (f32 plain cached), B = w (LDS), K=1024
  float4 pf[8];
  auto ldx = [&](int kc) {
#pragma unroll
    for (int rnd = 0; rnd < 4; ++rnd) {
      int idx = rnd * 2048 + tid * 8, b = idx >> 7, c = idx & 127;
      const float* p = &x[(b * TT + t) * INN + kc * 128 + c];
      pf[rnd * 2] = *(const float4*)p;
      pf[rnd * 2 + 1] = *(const float4*)(p + 4);
    }
  };
  auto stx = [&](short* s) {
#pragma unroll
    for (int rnd = 0; rnd < 4; ++rnd) {
      int idx = rnd * 2048 + tid * 8, b = idx >> 7, c = idx & 127;
      float4 u = pf[rnd * 2], u2 = pf[rnd * 2 + 1];
      short8v sv;
      sv[0] = f2bf(u.x);  sv[1] = f2bf(u.y);  sv[2] = f2bf(u.z);  sv[3] = f2bf(u.w);
      sv[4] = f2bf(u2.x); sv[5] = f2bf(u2.y); sv[6] = f2bf(u2.z); sv[7] = f2bf(u2.w);
      *(short8v*)&s[b * 136 + c] = sv;
    }
  };
  float4v acc = {0.f, 0.f, 0.f, 0.f};
  ldx(0); stx(stg0);
  __syncthreads();
  for (int kc = 0; kc < 8; ++kc) {
    short* cur = (kc & 1) ? stg1 : stg0;
    short* nxt = (kc & 1) ? stg0 : stg1;
    if (kc < 7) ldx(kc + 1);
#pragma unroll
    for (int kk = 0; kk < 4; ++kk) {
      short8v af = *(const short8v*)&cur[(wv * 16 + col) * 136 + kk * 32 + q * 8];
      short8v bf = *(const short8v*)&w[col * 1032 + kc * 128 + kk * 32 + q * 8];
      acc = __builtin_amdgcn_mfma_f32_16x16x32_bf16(af, bf, acc, 0, 0, 0);
    }
    if (kc < 7) stx(nxt);
    __syncthreads();
  }

  // ---- LIF1 + publish l1 spikes (coherent) + tr1 to scr
  short* l1b = (short*)(ws + WS_L1B) + (t & 1) * (BB * HIDD);
  short* l1trT = (short*)(ws + WS_L1TRT) + (t & 1) * (HIDD * BB);
#pragma unroll
  for (int r = 0; r < 4; ++r) {
    float v = ALPHAF * v1[r] + SCLF * acc[r];
    float z = v > 1.0f ? 1.0f : 0.0f;
    v -= z;
    v1[r] = v;
    tr1[r] = DECAYF * tr1[r] + (1.0f - DECAYF) * z;
    int b = wv * 16 + q * 4 + r;
    out[O_L1SEQ + (b * TT + t) * HIDD + h0 + col] = z;
    cst16(&l1b[b * HIDD + h0 + col], f2bf(z));
    scr[col * 68 + b] = tr1[r];
    if (t == TT - 1) {
      out[O_V1 + b * HIDD + h0 + col] = v1[r];
      out[O_L1TR + b * HIDD + h0 + col] = tr1[r];
    }
  }
  __syncthreads();
  {  // publish l1_tr^T (16 h x 64 b), coherent 8B stores
    int idx = tid * 4, hl = idx >> 6, b0 = idx & 63;
    union { short4 s; u64 u; } cv;
    cv.s.x = f2bf(scr[hl * 68 + b0 + 0]);
    cv.s.y = f2bf(scr[hl * 68 + b0 + 1]);
    cv.s.z = f2bf(scr[hl * 68 + b0 + 2]);
    cv.s.w = f2bf(scr[hl * 68 + b0 + 3]);
    cst(&l1trT[(h0 + hl) * 64 + b0], cv.u);
  }

  // ---- outer1: w_in(LDS) update; B = in_tr^T chunks (coherent loads)
  const short* intrT = (const short*)(ws + WS_INTRT) + (t & 1) * (INN * BB);
  short8v afu[2];
#pragma unroll
  for (int kk = 0; kk < 2; ++kk) {
    short8v a;
#pragma unroll
    for (int j = 0; j < 8; ++j) a[j] = f2bf(scr[col * 68 + kk * 32 + q * 8 + j]);
    afu[kk] = a;
  }
  u64 pu[8];
  auto ldi = [&](int ci) {
#pragma unroll
    for (int rnd = 0; rnd < 4; ++rnd) {
      int idx = rnd * 2048 + tid * 8, r = idx >> 6, c = idx & 63;
      const short* p = &intrT[(ci * 128 + r) * 64 + c];
      pu[rnd * 2] = cld(p);
      pu[rnd * 2 + 1] = cld(p + 4);
    }
  };
  auto sti = [&](short* s) {
#pragma unroll
    for (int rnd = 0; rnd < 4; ++rnd) {
      int idx = rnd * 2048 + tid * 8, r = idx >> 6, c = idx & 63;
      *(u64*)&s[r * 72 + c] = pu[rnd * 2];
      *(u64*)&s[r * 72 + c + 4] = pu[rnd * 2 + 1];
    }
  };
  const float c0 = 1.0f - LRF * WDF, c1 = LRF / 64.0f;
  ldi(0); sti(stg0);
  __syncthreads();
  for (int ci = 0; ci < 8; ++ci) {
    short* cur = (ci & 1) ? stg1 : stg0;
    short* nxt = (ci & 1) ? stg0 : stg1;
    if (ci < 7) ldi(ci + 1);
#pragma unroll
    for (int j = 0; j < 2; ++j) {
      int nt = wv * 2 + j;
      float4v au = {0.f, 0.f, 0.f, 0.f};
#pragma unroll
      for (int kk = 0; kk < 2; ++kk) {
        short8v bf = *(const short8v*)&cur[(nt * 16 + col) * 72 + kk * 32 + q * 8];
        au = __builtin_amdgcn_mfma_f32_16x16x32_bf16(afu[kk], bf, au, 0, 0, 0);
      }
#pragma unroll
      for (int r = 0; r < 4; ++r) {
        int hrow = q * 4 + r, icol = ci * 128 + nt * 16 + col;
        float ow = bf2f(w[hrow * 1032 + icol]);
        w[hrow * 1032 + icol] = f2bf(ow * c0 + c1 * au[r]);
      }
    }
    if (ci < 7) sti(nxt);
    __syncthreads();
  }
}

// ================= layer-2 block: o-tile = idx16*16 =================
// LDS: w2b bf16 [16][2056] @0 (65792); stg0 @65792; stg1 @84224 (each 18432);
//      scr f32 [16][68] @102656
__device__ void l2_work(int tp, int idx16, int tid, float* __restrict__ out,
                        char* __restrict__ ws, float* __restrict__ w_hid,
                        short* w2b, short* stg0, short* stg1, float* scr,
                        float4v& v2, float4v& tr2) {
  const int o0 = idx16 * 16, wv = tid >> 6, lane = tid & 63;
  const int col = lane & 15, q = lane >> 4;
  const short* l1b = (const short*)(ws + WS_L1B) + (tp & 1) * (BB * HIDD);

  // ---- refresh bf16 copy of w_hid rows (plain cached loads; block-private)
#pragma unroll
  for (int rnd = 0; rnd < 16; ++rnd) {
    int idx = rnd * 2048 + tid * 8, r = idx >> 11, c = idx & 2047;
    const float* p = &w_hid[(o0 + r) * HIDD + c];
    float4 a = *(const float4*)p, b = *(const float4*)(p + 4);
    short8v sv;
    sv[0] = f2bf(a.x); sv[1] = f2bf(a.y); sv[2] = f2bf(a.z); sv[3] = f2bf(a.w);
    sv[4] = f2bf(b.x); sv[5] = f2bf(b.y); sv[6] = f2bf(b.z); sv[7] = f2bf(b.w);
    *(short8v*)&w2b[r * 2056 + c] = sv;
  }

  // ---- gemm2: cur2[64b x 16o], A = l1b (coherent), B = w2b (LDS), K=2048
  u64 pu[8];
  auto ldl = [&](int kc) {
#pragma unroll
    for (int rnd = 0; rnd < 4; ++rnd) {
      int idx = rnd * 2048 + tid * 8, r = idx >> 7, c = idx & 127;
      const short* p = &l1b[r * HIDD + kc * 128 + c];
      pu[rnd * 2] = cld(p);
      pu[rnd * 2 + 1] = cld(p + 4);
    }
  };
  auto stl = [&](short* s) {
#pragma unroll
    for (int rnd = 0; rnd < 4; ++rnd) {
      int idx = rnd * 2048 + tid * 8, r = idx >> 7, c = idx & 127;
      *(u64*)&s[r * 136 + c] = pu[rnd * 2];
      *(u64*)&s[r * 136 + c + 4] = pu[rnd * 2 + 1];
    }
  };
  float4v acc = {0.f, 0.f, 0.f, 0.f};
  ldl(0); stl(stg0);
  __syncthreads();
  for (int kc = 0; kc < 16; ++kc) {
    short* cur = (kc & 1) ? stg1 : stg0;
    short* nxt = (kc & 1) ? stg0 : stg1;
    if (kc < 15) ldl(kc + 1);
#pragma unroll
    for (int kk = 0; kk < 4; ++kk) {
      short8v af = *(const short8v*)&cur[(wv * 16 + col) * 136 + kk * 32 + q * 8];
      short8v bf = *(const short8v*)&w2b[col * 2056 + kc * 128 + kk * 32 + q * 8];
      acc = __builtin_amdgcn_mfma_f32_16x16x32_bf16(af, bf, acc, 0, 0, 0);
    }
    if (kc < 15) stl(nxt);
    __syncthreads();
  }

  // ---- LIF2
#pragma unroll
  for (int r = 0; r < 4; ++r) {
    float v = ALPHAF * v2[r] + SCLF * acc[r];
    float z = v > 1.0f ? 1.0f : 0.0f;
    v -= z;
    v2[r] = v;
    tr2[r] = DECAYF * tr2[r] + (1.0f - DECAYF) * z;
    int b = wv * 16 + q * 4 + r;
    out[O_L2SEQ + (b * TT + tp) * OUTT + o0 + col] = z;
    scr[col * 68 + b] = tr2[r];
    if (tp == TT - 1) {
      out[O_V2 + b * OUTT + o0 + col] = v2[r];
      out[O_L2TR + b * OUTT + o0 + col] = tr2[r];
    }
  }
  __syncthreads();

  // ---- outer2: w_hid (global f32, block-private) update; B = l1_tr^T (coherent)
  const short* l1trT = (const short*)(ws + WS_L1TRT) + (tp & 1) * (HIDD * BB);
  short8v afu[2];
#pragma unroll
  for (int kk = 0; kk < 2; ++kk) {
    short8v a;
#pragma unroll
    for (int j = 0; j < 8; ++j) a[j] = f2bf(scr[col * 68 + kk * 32 + q * 8 + j]);
    afu[kk] = a;
  }
  auto ldt = [&](int ci) {
#pragma unroll
    for (int rnd = 0; rnd < 4; ++rnd) {
      int idx = rnd * 2048 + tid * 8, r = idx >> 6, c = idx & 63;
      const short* p = &l1trT[(ci * 128 + r) * 64 + c];
      pu[rnd * 2] = cld(p);
      pu[rnd * 2 + 1] = cld(p + 4);
    }
  };
  auto stt = [&](short* s) {
#pragma unroll
    for (int rnd = 0; rnd < 4; ++rnd) {
      int idx = rnd * 2048 + tid * 8, r = idx >> 6, c = idx & 63;
      *(u64*)&s[r * 72 + c] = pu[rnd * 2];
      *(u64*)&s[r * 72 + c + 4] = pu[rnd * 2 + 1];
    }
  };
  const float c0 = 1.0f - LRF * WDF, c1 = LRF / 64.0f;
  ldt(0); stt(stg0);
  __syncthreads();
  for (int ci = 0; ci < 16; ++ci) {
    short* cur = (ci & 1) ? stg1 : stg0;
    short* nxt = (ci & 1) ? stg0 : stg1;
    if (ci < 15) ldt(ci + 1);
#pragma unroll
    for (int j = 0; j < 2; ++j) {
      int nt = wv * 2 + j;
      float4v au = {0.f, 0.f, 0.f, 0.f};
#pragma unroll
      for (int kk = 0; kk < 2; ++kk) {
        short8v bf = *(const short8v*)&cur[(nt * 16 + col) * 72 + kk * 32 + q * 8];
        au = __builtin_amdgcn_mfma_f32_16x16x32_bf16(afu[kk], bf, au, 0, 0, 0);
      }
#pragma unroll
      for (int r = 0; r < 4; ++r) {
        float* p = &w_hid[(o0 + q * 4 + r) * HIDD + ci * 128 + nt * 16 + col];
        *p = *p * c0 + c1 * au[r];
      }
    }
    if (ci < 15) stt(nxt);
    __syncthreads();
  }
}

// ================= helper block: in_tr state in LDS; publish in_tr^T(tt) =================
// LDS: intr f32 [64][132] @0 (33792)
__device__ void helper_work(int tt, int hidx, int tid, const float* __restrict__ x,
                            char* __restrict__ ws, float* intr) {
  const int i0 = hidx * 128;
  short* intrT = (short*)(ws + WS_INTRT) + (tt & 1) * (INN * BB);
#pragma unroll
  for (int rnd = 0; rnd < 4; ++rnd) {
    int idx = rnd * 2048 + tid * 8, b = idx >> 7, c = idx & 127;
    const float* xs = &x[(b * TT + tt) * INN + i0 + c];
    float4 xa = *(const float4*)xs, xb = *(const float4*)(xs + 4);
    float* ip = &intr[b * 132 + c];
    float4 p1 = *(const float4*)ip, p2 = *(const float4*)(ip + 4);
    float4 n1, n2;
    n1.x = DECAYF * p1.x + (1.0f - DECAYF) * xa.x;
    n1.y = DECAYF * p1.y + (1.0f - DECAYF) * xa.y;
    n1.z = DECAYF * p1.z + (1.0f - DECAYF) * xa.z;
    n1.w = DECAYF * p1.w + (1.0f - DECAYF) * xa.w;
    n2.x = DECAYF * p2.x + (1.0f - DECAYF) * xb.x;
    n2.y = DECAYF * p2.y + (1.0f - DECAYF) * xb.y;
    n2.z = DECAYF * p2.z + (1.0f - DECAYF) * xb.z;
    n2.w = DECAYF * p2.w + (1.0f - DECAYF) * xb.w;
    *(float4*)ip = n1;
    *(float4*)(ip + 4) = n2;
  }
  __syncthreads();
  // transposed publish: rows = i (128), cols = b (64); coherent 8B stores
#pragma unroll
  for (int rnd = 0; rnd < 4; ++rnd) {
    int idx = rnd * 2048 + tid * 8, il = idx >> 6, b0 = idx & 63;
    union { short4 s; u64 u; } cv0, cv1;
    cv0.s.x = f2bf(intr[(b0 + 0) * 132 + il]);
    cv0.s.y = f2bf(intr[(b0 + 1) * 132 + il]);
    cv0.s.z = f2bf(intr[(b0 + 2) * 132 + il]);
    cv0.s.w = f2bf(intr[(b0 + 3) * 132 + il]);
    cv1.s.x = f2bf(intr[(b0 + 4) * 132 + il]);
    cv1.s.y = f2bf(intr[(b0 + 5) * 132 + il]);
    cv1.s.z = f2bf(intr[(b0 + 6) * 132 + il]);
    cv1.s.w = f2bf(intr[(b0 + 7) * 132 + il]);
    cst(&intrT[(i0 + il) * 64 + b0], cv0.u);
    cst(&intrT[(i0 + il) * 64 + b0 + 4], cv1.u);
  }
  __syncthreads();
}

// ---- init: zero the barrier counter (coherent) ----
__global__ __launch_bounds__(64) void k_init(char* __restrict__ ws) {
  if (threadIdx.x == 0)
    __hip_atomic_store((unsigned*)(ws + WS_BAR), 0u,
                       __ATOMIC_RELAXED, __HIP_MEMORY_SCOPE_AGENT);
}

__global__ __launch_bounds__(256) void k_persist(const float* __restrict__ x,
                                                 const float* __restrict__ w_in,
                                                 float* __restrict__ w_hid,
                                                 float* __restrict__ out,
                                                 char* __restrict__ ws) {
  __shared__ __align__(16) char smem[107008];
  const int bid = blockIdx.x, tid = threadIdx.x;
  unsigned* cnt = (unsigned*)(ws + WS_BAR);
  unsigned barord = 0;
  float4v vst = {0.f, 0.f, 0.f, 0.f};   // v1 / v2 (persistent, registers)
  float4v trs = {0.f, 0.f, 0.f, 0.f};   // l1_tr / l2_tr

  // ---- prologue
  if (bid < N_L1) {
    // load w_in tile [16h x 1024] f32 -> bf16 LDS (only global read of w_in)
    short* w = (short*)smem;
    int r = tid >> 4, c0 = (tid & 15) * 64;
    for (int cc = 0; cc < 64; cc += 4) {
      float4 u = *(const float4*)&w_in[(bid * 16 + r) * INN + c0 + cc];
      short4 s;
      s.x = f2bf(u.x); s.y = f2bf(u.y); s.z = f2bf(u.z); s.w = f2bf(u.w);
      *(short4*)&w[r * 1032 + c0 + cc] = s;
    }
  } else if (bid >= N_L1 + N_L2) {
    float* intr = (float*)smem;
    for (int e = tid; e < 64 * 132; e += 256) intr[e] = 0.f;
    __syncthreads();
    helper_work(0, bid - (N_L1 + N_L2), tid, x, ws, intr);
  }
  gbar(cnt, ++barord * NBLK, tid);

  // ---- supersteps: L1 does step t, L2 does step t-1, helpers prepare t+1
  for (int t = 0; t <= TT; ++t) {
    if (bid < N_L1) {
      if (t < TT)
        l1_work(t, bid, tid, x, out, ws, (short*)smem, (short*)(smem + 33024),
                (short*)(smem + 51456), (float*)(smem + 69888), vst, trs);
    } else if (bid < N_L1 + N_L2) {
      if (t >= 1)
        l2_work(t - 1, bid - N_L1, tid, out, ws, w_hid, (short*)smem,
                (short*)(smem + 65792), (short*)(smem + 84224),
                (float*)(smem + 102656), vst, trs);
    } else {
      if (t + 1 < TT)
        helper_work(t + 1, bid - (N_L1 + N_L2), tid, x, ws, (float*)smem);
    }
    if (t < TT) gbar(cnt, ++barord * NBLK, tid);
  }
}

extern "C" void kernel_launch(void* const* d_in, const int* in_sizes, int n_in,
                              void* d_out, int out_size, void* d_ws, size_t ws_size,
                              hipStream_t stream) {
  const float* x = (const float*)d_in[0];
  const float* w_in = (const float*)d_in[1];
  float* w_hid = (float*)d_in[2];   // mutated in place; harness restores each launch
  float* out = (float*)d_out;
  char* ws = (char*)d_ws;

  hipLaunchKernelGGL(k_init, dim3(1), dim3(64), 0, stream, ws);
  hipLaunchKernelGGL(k_persist, dim3(NBLK), dim3(256), 0, stream, x, w_in, w_hid, out, ws);
}